// Round 16
// baseline (744.697 us; speedup 1.0000x reference)
//
#include <hip/hip_runtime.h>
#include <hip/hip_fp16.h>

#define NN 100000
#define NE 1600000
#define NT (NE + NN)      // edges + self-loops
#define DD 128
#define NL 5
#define NB 62
#define BN_EPS 1e-5f
#define NBUCK 391         // ceil(NN/256); bucket = node_id >> 8
#define PSUMNB 6250       // = NN/16 = k_agg grid size (exact)
#define RED1 128          // stage-1 BN-reduce blocks (49 rows each)

typedef unsigned short ushort_t;
typedef unsigned int uint_t;
typedef _Float16 h8 __attribute__((ext_vector_type(8)));   // 8 fp16 (4 VGPRs)
typedef float f32x4 __attribute__((ext_vector_type(4)));

static __device__ __forceinline__ float4 ld4(const float* p) { return *(const float4*)p; }

static __device__ __forceinline__ __half2 u2h2(uint_t u) {
    return __builtin_bit_cast(__half2, u);
}
static __device__ __forceinline__ uint_t h22u(__half2 h) {
    return __builtin_bit_cast(uint_t, h);
}
static __device__ __forceinline__ uint_t pkh(float a, float b) {   // pack 2 f32 -> half2
    return h22u(__float22half2_rn(make_float2(a, b)));
}

// packed fp16 edge accumulation: acc[j] += nr2 * (h[j] + e[j])
static __device__ __forceinline__ void accumh(__half2* acc, uint4 hv, uint4 ev,
                                              uint_t nr) {
    __half2 n2 = u2h2(nr);
    const uint_t* ph = (const uint_t*)&hv;
    const uint_t* pe = (const uint_t*)&ev;
#pragma unroll
    for (int j = 0; j < 4; ++j)
        acc[j] = __hfma2(n2, __hadd2(u2h2(ph[j]), u2h2(pe[j])), acc[j]);
}

// ---------------- setup kernels ----------------

__global__ void k_init(int* gbh_d, int* gbh_s, float* scale, float* shift,
                       int* row_ptr) {
    int i = blockIdx.x * 256 + threadIdx.x;
    if (i < NBUCK) { gbh_d[i] = 0; gbh_s[i] = 0; }
    if (i < DD) { scale[i] = 1.f; shift[i] = 0.f; }
    if (i == 0) row_ptr[NN] = NT;            // total is static
}

// convert edge_tab (L*NB*DD) and lin_w (L*DD*DD) fp32 -> fp16 once
__global__ void k_cvt(const float* __restrict__ src, ushort_t* __restrict__ dst,
                      int total) {
    int i = blockIdx.x * 256 + threadIdx.x;
    if (i < total) {
        __half h = __float2half_rn(src[i]);
        dst[i] = __builtin_bit_cast(ushort_t, h);
    }
}

// coarse bucket histograms: dst over NT items, src over NE edges. LDS-privatized.
__global__ __launch_bounds__(256) void k_binhist(const int* __restrict__ ei,
                                                 int* __restrict__ gbh_d,
                                                 int* __restrict__ gbh_s) {
    __shared__ int hd[NBUCK], hs[NBUCK];
    int tid = threadIdx.x;
    for (int b = tid; b < NBUCK; b += 256) { hd[b] = 0; hs[b] = 0; }
    __syncthreads();
    for (int idx = blockIdx.x * 256 + tid; idx < NT; idx += gridDim.x * 256) {
        int d = (idx < NE) ? ei[NE + idx] : idx - NE;
        atomicAdd(&hd[d >> 8], 1);
        if (idx < NE) atomicAdd(&hs[ei[idx] >> 8], 1);
    }
    __syncthreads();
    for (int b = tid; b < NBUCK; b += 256) {
        if (hd[b]) atomicAdd(&gbh_d[b], hd[b]);
        if (hs[b]) atomicAdd(&gbh_s[b], hs[b]);
    }
}

// scan both 391-entry histograms -> bases [NBUCK+1] and cursors
__global__ void k_scan391(const int* __restrict__ gbh_d, const int* __restrict__ gbh_s,
                          int* __restrict__ bb_d, int* __restrict__ cur_d,
                          int* __restrict__ bb_s, int* __restrict__ cur_s) {
    __shared__ int s[512];
    const int* g = blockIdx.x ? gbh_s : gbh_d;
    int* bb = blockIdx.x ? bb_s : bb_d;
    int* cur = blockIdx.x ? cur_s : cur_d;
    int t = threadIdx.x;
    int v = (t < NBUCK) ? g[t] : 0;
    s[t] = v;
    __syncthreads();
    for (int off = 1; off < 512; off <<= 1) {
        int val = (t >= off) ? s[t - off] : 0;
        __syncthreads();
        s[t] += val;
        __syncthreads();
    }
    if (t < NBUCK) { int e = s[t] - v; bb[t] = e; cur[t] = e; }
    if (t == 511) bb[NBUCK] = s[511];
}

// merged scatter: one pass over ei emits dst-records (NT) AND src-records (NE)
#define CHUNK 4096
__global__ __launch_bounds__(256) void k_scat2(const int* __restrict__ ei,
                                               const int* __restrict__ ea,
                                               int* __restrict__ cur_d,
                                               int* __restrict__ cur_s,
                                               uint_t* __restrict__ rec_d,
                                               int* __restrict__ rec_s) {
    __shared__ int lhd[NBUCK], lbd[NBUCK], lhs[NBUCK], lbs[NBUCK];
    int tid = threadIdx.x;
    for (int b = tid; b < NBUCK; b += 256) { lhd[b] = 0; lhs[b] = 0; }
    __syncthreads();
    int base = blockIdx.x * CHUNK;
    uint_t rd[16];
    int rs[16], bkd[16], bks[16];
#pragma unroll
    for (int k = 0; k < 16; ++k) {
        int idx = base + tid + k * 256;
        bkd[k] = -1; bks[k] = -1;
        if (idx < NT) {
            int s, d, eid;
            if (idx < NE) {
                s = ei[idx]; d = ei[NE + idx]; eid = ea[idx];
                bks[k] = s >> 8; rs[k] = s;
                atomicAdd(&lhs[bks[k]], 1);
            } else {
                s = d = idx - NE; eid = 0;
            }
            bkd[k] = d >> 8;
            rd[k] = (uint_t)s | ((uint_t)eid << 17) | ((uint_t)(d & 255) << 24);
            atomicAdd(&lhd[bkd[k]], 1);
        }
    }
    __syncthreads();
    for (int b = tid; b < NBUCK; b += 256) {
        if (lhd[b]) lbd[b] = atomicAdd(&cur_d[b], lhd[b]);
        if (lhs[b]) lbs[b] = atomicAdd(&cur_s[b], lhs[b]);
    }
    __syncthreads();
    for (int b = tid; b < NBUCK; b += 256) { lhd[b] = 0; lhs[b] = 0; }
    __syncthreads();
#pragma unroll
    for (int k = 0; k < 16; ++k) {
        if (bkd[k] >= 0) {
            int rk = atomicAdd(&lhd[bkd[k]], 1);
            rec_d[lbd[bkd[k]] + rk] = rd[k];
        }
        if (bks[k] >= 0) {
            int rk = atomicAdd(&lhs[bks[k]], 1);
            rec_s[lbs[bks[k]] + rk] = rs[k];
        }
    }
}

// per-bucket exact src histogram -> dinv (deg = count + 1 self-loop)
__global__ __launch_bounds__(256) void k_srcfin(const int* __restrict__ rec,
                                                const int* __restrict__ bb,
                                                float* __restrict__ dinv) {
    __shared__ int h[256];
    int tid = threadIdx.x;
    h[tid] = 0;
    __syncthreads();
    int lo = bb[blockIdx.x], hi = bb[blockIdx.x + 1];
    for (int i = lo + tid; i < hi; i += 256) atomicAdd(&h[rec[i] & 255], 1);
    __syncthreads();
    int v = blockIdx.x * 256 + tid;
    if (v < NN) dinv[v] = rsqrtf((float)(h[tid] + 1));
}

// per-bucket: exact dst hist -> row_ptr; ranked re-scatter -> final CSR.
// norm stored PRE-PACKED as half2 (both lanes = norm).
__global__ __launch_bounds__(256) void k_dstfin(const uint_t* __restrict__ rec,
                                                const int* __restrict__ bb,
                                                const float* __restrict__ dinv,
                                                int* __restrict__ row_ptr,
                                                int* __restrict__ s_pack,
                                                uint_t* __restrict__ s_normh) {
    __shared__ int h[256], sc[256], rpE[256];
    int tid = threadIdx.x;
    h[tid] = 0;
    __syncthreads();
    int lo = bb[blockIdx.x], hi = bb[blockIdx.x + 1];
    for (int i = lo + tid; i < hi; i += 256) atomicAdd(&h[(rec[i] >> 24) & 255], 1);
    __syncthreads();
    sc[tid] = h[tid];
    __syncthreads();
    for (int off = 1; off < 256; off <<= 1) {
        int val = (tid >= off) ? sc[tid - off] : 0;
        __syncthreads();
        sc[tid] += val;
        __syncthreads();
    }
    rpE[tid] = sc[tid] - h[tid];       // exclusive
    int v = blockIdx.x * 256 + tid;
    if (v < NN) row_ptr[v] = lo + rpE[tid];
    h[tid] = 0;
    __syncthreads();
    for (int i = lo + tid; i < hi; i += 256) {
        uint_t u = rec[i];
        int dl = (u >> 24) & 255;
        int rk = atomicAdd(&h[dl], 1);
        int slot = lo + rpE[dl] + rk;
        int s = u & 0x1FFFF;
        int e = (u >> 17) & 0x3F;
        float nm = dinv[s] * dinv[(blockIdx.x << 8) + dl];
        s_pack[slot] = s | (e << 20);
        s_normh[slot] = h22u(__half2half2(__float2half_rn(nm)));
    }
}

// h0 -> fp16 Xh
__global__ void k_h0b(const int* __restrict__ x, const float* __restrict__ emb,
                      ushort_t* __restrict__ Xh, int n) {
    int v = blockIdx.x * 16 + (threadIdx.x >> 4);
    if (v >= n) return;
    int c8 = (threadIdx.x & 15) * 8;
    const float* src = &emb[x[v] * DD + c8];
    uint_t pk[4];
#pragma unroll
    for (int j = 0; j < 4; ++j) pk[j] = pkh(src[2 * j], src[2 * j + 1]);
    *(uint4*)&Xh[(size_t)v * DD + c8] = make_uint4(pk[0], pk[1], pk[2], pk[3]);
}

// ---------------- per-layer kernels ----------------

// apply BN(scale,shift)+optional ReLU to 8 packed fp16, repack to h8 frag
static __device__ __forceinline__ h8 bn8h(uint4 v, float4 sc0, float4 sc1,
                                          float4 sh0, float4 sh1, int relu) {
    const uint_t* pv = (const uint_t*)&v;
    float f[8];
    float2 t;
    t = __half22float2(u2h2(pv[0])); f[0] = t.x; f[1] = t.y;
    t = __half22float2(u2h2(pv[1])); f[2] = t.x; f[3] = t.y;
    t = __half22float2(u2h2(pv[2])); f[4] = t.x; f[5] = t.y;
    t = __half22float2(u2h2(pv[3])); f[6] = t.x; f[7] = t.y;
    f[0] = fmaf(f[0], sc0.x, sh0.x); f[1] = fmaf(f[1], sc0.y, sh0.y);
    f[2] = fmaf(f[2], sc0.z, sh0.z); f[3] = fmaf(f[3], sc0.w, sh0.w);
    f[4] = fmaf(f[4], sc1.x, sh1.x); f[5] = fmaf(f[5], sc1.y, sh1.y);
    f[6] = fmaf(f[6], sc1.z, sh1.z); f[7] = fmaf(f[7], sc1.w, sh1.w);
    if (relu) {
#pragma unroll
        for (int j = 0; j < 8; ++j) f[j] = fmaxf(f[j], 0.f);
    }
    uint4 r;
    r.x = pkh(f[0], f[1]); r.y = pkh(f[2], f[3]);
    r.z = pkh(f[4], f[5]); r.w = pkh(f[6], f[7]);
    return __builtin_bit_cast(h8, r);
}

// LDS-free MFMA fp16 GEMM with swapped operands (packed row-major stores).
__global__ __launch_bounds__(256, 3) void k_gemm(const ushort_t* __restrict__ Xh,
                                                 const ushort_t* __restrict__ Wh,
                                                 const float* __restrict__ bias,
                                                 const float* __restrict__ scale,
                                                 const float* __restrict__ shift,
                                                 ushort_t* __restrict__ C,
                                                 int n, int relu) {
    const int tid = threadIdx.x;
    const int r0 = blockIdx.x * 128;
    const int w = tid >> 6;           // wave 0..3 -> rows w*32..+32
    const int lane = tid & 63;
    const int lr = lane & 15;         // X-row / W-row within 16
    const int lg = lane >> 4;         // k-subgroup 0..3

    f32x4 acc[2][8];
#pragma unroll
    for (int rf = 0; rf < 2; ++rf)
#pragma unroll
        for (int cf = 0; cf < 8; ++cf)
#pragma unroll
            for (int r = 0; r < 4; ++r) acc[rf][cf][r] = 0.f;

#pragma unroll
    for (int ks = 0; ks < 4; ++ks) {
        const int kb = (ks * 4 + lg) * 8;          // this lane's k-base (8 fp16)
        float4 sc0 = ld4(&scale[kb]), sc1 = ld4(&scale[kb + 4]);
        float4 sh0 = ld4(&shift[kb]), sh1 = ld4(&shift[kb + 4]);

        int row0 = r0 + w * 32 + lr;
        int row1 = row0 + 16;
        uint4 va = make_uint4(0, 0, 0, 0), vb = make_uint4(0, 0, 0, 0);
        if (row0 < n) va = *(const uint4*)&Xh[(size_t)row0 * DD + kb];
        if (row1 < n) vb = *(const uint4*)&Xh[(size_t)row1 * DD + kb];
        h8 a0 = bn8h(va, sc0, sc1, sh0, sh1, relu);
        h8 a1 = bn8h(vb, sc0, sc1, sh0, sh1, relu);

#pragma unroll
        for (int cf = 0; cf < 8; ++cf) {
            int col = cf * 16 + lr;
            h8 b = *(const h8*)&Wh[(size_t)col * DD + kb];
            // swapped: W as "A" (D-rows = W-cols), X as "B" (D-cols = X-rows)
            acc[0][cf] = __builtin_amdgcn_mfma_f32_16x16x32_f16(b, a0, acc[0][cf], 0, 0, 0);
            acc[1][cf] = __builtin_amdgcn_mfma_f32_16x16x32_f16(b, a1, acc[1][cf], 0, 0, 0);
        }
    }

    // epilogue: lane owns output row (r0+w*32+rf*16+lr), cols cf*16+lg*4+{0..3}
#pragma unroll
    for (int rf = 0; rf < 2; ++rf) {
        int grow = r0 + w * 32 + rf * 16 + lr;
        if (grow < n) {
#pragma unroll
            for (int cf = 0; cf < 8; ++cf) {
                int c0 = cf * 16 + lg * 4;
                float4 bi = ld4(&bias[c0]);
                uint_t lo = pkh(acc[rf][cf][0] + bi.x, acc[rf][cf][1] + bi.y);
                uint_t hi = pkh(acc[rf][cf][2] + bi.z, acc[rf][cf][3] + bi.w);
                *(uint2*)&C[(size_t)grow * DD + c0] = make_uint2(lo, hi);
            }
        }
    }
}

// agg + fused BN partials. 16 lanes/node, 8x batched gathers, packed fp16 math.
__global__ __launch_bounds__(256) void k_agg(const ushort_t* __restrict__ hl,
                                             const ushort_t* __restrict__ etab,
                                             const int* __restrict__ row_ptr,
                                             const int* __restrict__ s_pack,
                                             const uint_t* __restrict__ s_normh,
                                             ushort_t* __restrict__ aggb,
                                             float* __restrict__ psumA,
                                             float* __restrict__ psumB, int n) {
    __shared__ float lsA[4][DD], lsB[4][DD];
    int tid = threadIdx.x;

    int v = blockIdx.x * 16 + (tid >> 4);      // always < n (exact grid)
    int lane8 = (tid & 15) * 8;
    int p0 = row_ptr[v], p1 = row_ptr[v + 1];
    __half2 acc4[4];
#pragma unroll
    for (int j = 0; j < 4; ++j) acc4[j] = u2h2(0u);

    int p = p0;
    for (; p + 8 <= p1; p += 8) {
        int c[8]; uint_t nr[8]; uint4 h[8], e[8];
#pragma unroll
        for (int q = 0; q < 8; ++q) c[q] = s_pack[p + q];
#pragma unroll
        for (int q = 0; q < 8; ++q) nr[q] = s_normh[p + q];
#pragma unroll
        for (int q = 0; q < 8; ++q)
            h[q] = *(const uint4*)&hl[(size_t)(c[q] & 0xFFFFF) * DD + lane8];
#pragma unroll
        for (int q = 0; q < 8; ++q)
            e[q] = *(const uint4*)&etab[(c[q] >> 20) * DD + lane8];
#pragma unroll
        for (int q = 0; q < 8; ++q) accumh(acc4, h[q], e[q], nr[q]);
    }
    for (; p + 4 <= p1; p += 4) {
        int c[4]; uint_t nr[4]; uint4 h[4], e[4];
#pragma unroll
        for (int q = 0; q < 4; ++q) c[q] = s_pack[p + q];
#pragma unroll
        for (int q = 0; q < 4; ++q) nr[q] = s_normh[p + q];
#pragma unroll
        for (int q = 0; q < 4; ++q)
            h[q] = *(const uint4*)&hl[(size_t)(c[q] & 0xFFFFF) * DD + lane8];
#pragma unroll
        for (int q = 0; q < 4; ++q)
            e[q] = *(const uint4*)&etab[(c[q] >> 20) * DD + lane8];
#pragma unroll
        for (int q = 0; q < 4; ++q) accumh(acc4, h[q], e[q], nr[q]);
    }
    for (; p < p1; ++p) {
        int c = s_pack[p];
        uint_t nr = s_normh[p];
        uint4 hv = *(const uint4*)&hl[(size_t)(c & 0xFFFFF) * DD + lane8];
        uint4 ev = *(const uint4*)&etab[(c >> 20) * DD + lane8];
        accumh(acc4, hv, ev, nr);
    }

    // store packed fp16 agg directly
    uint4 st;
    st.x = h22u(acc4[0]); st.y = h22u(acc4[1]);
    st.z = h22u(acc4[2]); st.w = h22u(acc4[3]);
    *(uint4*)&aggb[(size_t)v * DD + lane8] = st;

    // BN partials in f32
    float f[8];
    float2 t;
    t = __half22float2(acc4[0]); f[0] = t.x; f[1] = t.y;
    t = __half22float2(acc4[1]); f[2] = t.x; f[3] = t.y;
    t = __half22float2(acc4[2]); f[4] = t.x; f[5] = t.y;
    t = __half22float2(acc4[3]); f[6] = t.x; f[7] = t.y;

    float s0[8], s1[8];
#pragma unroll
    for (int j = 0; j < 8; ++j) { s0[j] = f[j]; s1[j] = f[j] * f[j]; }
#pragma unroll
    for (int m = 16; m <= 32; m <<= 1) {
#pragma unroll
        for (int j = 0; j < 8; ++j) {
            s0[j] += __shfl_xor(s0[j], m);
            s1[j] += __shfl_xor(s1[j], m);
        }
    }
    int wv = tid >> 6;
    int lane = tid & 63;
    if (lane < 16) {
#pragma unroll
        for (int j = 0; j < 8; ++j) {
            lsA[wv][lane8 + j] = s0[j];
            lsB[wv][lane8 + j] = s1[j];
        }
    }
    __syncthreads();
    if (tid < DD) {
        psumA[(size_t)blockIdx.x * DD + tid] =
            lsA[0][tid] + lsA[1][tid] + lsA[2][tid] + lsA[3][tid];
        psumB[(size_t)blockIdx.x * DD + tid] =
            lsB[0][tid] + lsB[1][tid] + lsB[2][tid] + lsB[3][tid];
    }
}

// stage-1 BN reduce: coalesced row reads, 128 blocks x 49 rows
__global__ __launch_bounds__(256) void k_bnred(const float* __restrict__ psumA,
                                               const float* __restrict__ psumB,
                                               float* __restrict__ partA,
                                               float* __restrict__ partB) {
    __shared__ float sa[2][DD], sb[2][DD];
    int d = threadIdx.x & 127;
    int half = threadIdx.x >> 7;
    float a = 0.f, b = 0.f;
    int iend = min(blockIdx.x * 49 + 49, PSUMNB);
    for (int i = blockIdx.x * 49 + half; i < iend; i += 2) {
        a += psumA[(size_t)i * DD + d];
        b += psumB[(size_t)i * DD + d];
    }
    sa[half][d] = a; sb[half][d] = b;
    __syncthreads();
    if (threadIdx.x < DD) {
        partA[blockIdx.x * DD + d] = sa[0][d] + sa[1][d];
        partB[blockIdx.x * DD + d] = sb[0][d] + sb[1][d];
    }
}

// final BN: reduce RED1 partials, emit scale/shift
__global__ __launch_bounds__(256) void k_bnfin(const float* __restrict__ partA,
                                               const float* __restrict__ partB,
                                               const float* __restrict__ gamma,
                                               const float* __restrict__ beta,
                                               float* __restrict__ scale,
                                               float* __restrict__ shift, int n) {
    __shared__ float sa[2][DD], sb[2][DD];
    int d = threadIdx.x & 127;
    int half = threadIdx.x >> 7;
    float a = 0.f, b = 0.f;
    for (int i = half; i < RED1; i += 2) {
        a += partA[i * DD + d];
        b += partB[i * DD + d];
    }
    sa[half][d] = a; sb[half][d] = b;
    __syncthreads();
    if (threadIdx.x < DD) {
        float s = sa[0][d] + sa[1][d];
        float ss = sb[0][d] + sb[1][d];
        float mean = s / (float)n;
        float var = ss / (float)n - mean * mean;
        float sc = gamma[d] * rsqrtf(var + BN_EPS);
        scale[d] = sc;
        shift[d] = beta[d] - mean * sc;
    }
}

// final: out = fp16 Xh * scale + shift (fp32)
__global__ void k_bnapply(const ushort_t* __restrict__ Xh, float* __restrict__ out,
                          const float* __restrict__ scale,
                          const float* __restrict__ shift, int total8) {
    int i = blockIdx.x * blockDim.x + threadIdx.x;
    int stride = gridDim.x * blockDim.x;
    for (; i < total8; i += stride) {
        int c8 = (i & 15) * 8;
        uint4 v = *(const uint4*)&Xh[(size_t)i * 8];
        float4 sc0 = ld4(&scale[c8]), sc1 = ld4(&scale[c8 + 4]);
        float4 sh0 = ld4(&shift[c8]), sh1 = ld4(&shift[c8 + 4]);
        float2 t0 = __half22float2(u2h2(v.x));
        float2 t1 = __half22float2(u2h2(v.y));
        float2 t2 = __half22float2(u2h2(v.z));
        float2 t3 = __half22float2(u2h2(v.w));
        float4 o0, o1;
        o0.x = fmaf(t0.x, sc0.x, sh0.x);
        o0.y = fmaf(t0.y, sc0.y, sh0.y);
        o0.z = fmaf(t1.x, sc0.z, sh0.z);
        o0.w = fmaf(t1.y, sc0.w, sh0.w);
        o1.x = fmaf(t2.x, sc1.x, sh1.x);
        o1.y = fmaf(t2.y, sc1.y, sh1.y);
        o1.z = fmaf(t3.x, sc1.z, sh1.z);
        o1.w = fmaf(t3.y, sc1.w, sh1.w);
        *(float4*)&out[(size_t)i * 8] = o0;
        *(float4*)&out[(size_t)i * 8 + 4] = o1;
    }
}

// ---------------- launch ----------------

extern "C" void kernel_launch(void* const* d_in, const int* in_sizes, int n_in,
                              void* d_out, int out_size, void* d_ws, size_t ws_size,
                              hipStream_t stream) {
    const int* x        = (const int*)d_in[0];
    const int* ei       = (const int*)d_in[1];
    const int* ea       = (const int*)d_in[2];
    const float* x_emb  = (const float*)d_in[3];
    const float* lin_w  = (const float*)d_in[4];
    const float* lin_b  = (const float*)d_in[5];
    const float* etab   = (const float*)d_in[6];
    const float* gamma  = (const float*)d_in[7];
    const float* beta   = (const float*)d_in[8];
    float* OUT = (float*)d_out;

    char* w = (char*)d_ws;
    size_t off = 0;
    auto alloc = [&](size_t bytes) -> void* {
        off = (off + 255) & ~(size_t)255;
        void* p = w + off;
        off += bytes;
        return p;
    };
    ushort_t* Xh     = (ushort_t*)alloc((size_t)NN * DD * 2);
    ushort_t* hl     = (ushort_t*)alloc((size_t)NN * DD * 2);
    ushort_t* etabh  = (ushort_t*)alloc((size_t)NL * NB * DD * 2);
    ushort_t* Wh     = (ushort_t*)alloc((size_t)NL * DD * DD * 2);
    uint_t* rec_d    = (uint_t*)alloc((size_t)NT * 4);
    int*    rec_s    = (int*)alloc((size_t)NE * 4);
    int*   s_pack    = (int*)alloc((size_t)NT * 4);
    uint_t* s_normh  = (uint_t*)alloc((size_t)NT * 4);
    int*   rowp      = (int*)alloc((size_t)(NN + 1) * 4);
    float* dinv      = (float*)alloc((size_t)NN * 4);
    int*   gbh_d     = (int*)alloc((size_t)NBUCK * 4);
    int*   gbh_s     = (int*)alloc((size_t)NBUCK * 4);
    int*   bb_d      = (int*)alloc((size_t)(NBUCK + 1) * 4);
    int*   bb_s      = (int*)alloc((size_t)(NBUCK + 1) * 4);
    int*   cur_d     = (int*)alloc((size_t)NBUCK * 4);
    int*   cur_s     = (int*)alloc((size_t)NBUCK * 4);
    float* psumA     = (float*)alloc((size_t)DD * PSUMNB * 4);
    float* psumB     = (float*)alloc((size_t)DD * PSUMNB * 4);
    float* partA     = (float*)alloc((size_t)DD * RED1 * 4);
    float* partB     = (float*)alloc((size_t)DD * RED1 * 4);
    float* scale     = (float*)alloc((size_t)DD * 4);
    float* shift     = (float*)alloc((size_t)DD * 4);

    const int etabTot = NL * NB * DD;
    const int wTot = NL * DD * DD;

    k_init<<<(NN + 255) / 256, 256, 0, stream>>>(gbh_d, gbh_s, scale, shift, rowp);
    k_cvt<<<(etabTot + 255) / 256, 256, 0, stream>>>(etab, etabh, etabTot);
    k_cvt<<<(wTot + 255) / 256, 256, 0, stream>>>(lin_w, Wh, wTot);
    k_binhist<<<256, 256, 0, stream>>>(ei, gbh_d, gbh_s);
    k_scan391<<<2, 512, 0, stream>>>(gbh_d, gbh_s, bb_d, cur_d, bb_s, cur_s);
    k_scat2<<<(NT + CHUNK - 1) / CHUNK, 256, 0, stream>>>(ei, ea, cur_d, cur_s,
                                                          rec_d, rec_s);
    k_srcfin<<<NBUCK, 256, 0, stream>>>(rec_s, bb_s, dinv);
    k_dstfin<<<NBUCK, 256, 0, stream>>>(rec_d, bb_d, dinv, rowp, s_pack, s_normh);
    k_h0b<<<(NN + 15) / 16, 256, 0, stream>>>(x, x_emb, Xh, NN);

    for (int l = 0; l < NL; ++l) {
        k_gemm<<<(NN + 127) / 128, 256, 0, stream>>>(Xh, Wh + (size_t)l * DD * DD,
                                                     lin_b + (size_t)l * DD,
                                                     scale, shift, hl, NN, l > 0 ? 1 : 0);
        k_agg<<<PSUMNB, 256, 0, stream>>>(hl, etabh + (size_t)l * NB * DD,
                                          rowp, s_pack, s_normh, Xh, psumA, psumB, NN);
        k_bnred<<<RED1, 256, 0, stream>>>(psumA, psumB, partA, partB);
        k_bnfin<<<1, 256, 0, stream>>>(partA, partB, gamma + (size_t)l * DD,
                                       beta + (size_t)l * DD, scale, shift, NN);
    }
    k_bnapply<<<(NN * DD / 8 + 255) / 256, 256, 0, stream>>>(Xh, OUT, scale, shift,
                                                             NN * DD / 8);
}

// Round 17
// 730.663 us; speedup vs baseline: 1.0192x; 1.0192x over previous
//
#include <hip/hip_runtime.h>
#include <hip/hip_fp16.h>

#define NN 100000
#define NE 1600000
#define NT (NE + NN)      // edges + self-loops
#define DD 128
#define NL 5
#define NB 62
#define BN_EPS 1e-5f
#define NBUCK 391         // ceil(NN/256); bucket = node_id >> 8
#define PSUMNB 6250       // = NN/16 = k_agg grid size (exact)
#define RED1 128          // stage-1 BN-reduce blocks (49 rows each)

typedef unsigned short ushort_t;
typedef unsigned int uint_t;
typedef _Float16 h8 __attribute__((ext_vector_type(8)));   // 8 fp16 (4 VGPRs)
typedef float f32x4 __attribute__((ext_vector_type(4)));

static __device__ __forceinline__ float4 ld4(const float* p) { return *(const float4*)p; }

static __device__ __forceinline__ __half2 u2h2(uint_t u) {
    return __builtin_bit_cast(__half2, u);
}
static __device__ __forceinline__ uint_t h22u(__half2 h) {
    return __builtin_bit_cast(uint_t, h);
}
static __device__ __forceinline__ uint_t pkh(float a, float b) {   // pack 2 f32 -> half2
    return h22u(__float22half2_rn(make_float2(a, b)));
}

// packed fp16 edge accumulation: acc[j] += nr2 * (h[j] + e[j])
static __device__ __forceinline__ void accumh(__half2* acc, uint4 hv, uint4 ev,
                                              uint_t nr) {
    __half2 n2 = u2h2(nr);
    const uint_t* ph = (const uint_t*)&hv;
    const uint_t* pe = (const uint_t*)&ev;
#pragma unroll
    for (int j = 0; j < 4; ++j)
        acc[j] = __hfma2(n2, __hadd2(u2h2(ph[j]), u2h2(pe[j])), acc[j]);
}

// ---------------- setup kernels ----------------

__global__ void k_init(int* gbh_d, int* gbh_s, float* scale, float* shift,
                       int* row_ptr) {
    int i = blockIdx.x * 256 + threadIdx.x;
    if (i < NBUCK) { gbh_d[i] = 0; gbh_s[i] = 0; }
    if (i < DD) { scale[i] = 1.f; shift[i] = 0.f; }
    if (i == 0) row_ptr[NN] = NT;            // total is static
}

// convert edge_tab (L*NB*DD) and lin_w (L*DD*DD) fp32 -> fp16 once
__global__ void k_cvt(const float* __restrict__ src, ushort_t* __restrict__ dst,
                      int total) {
    int i = blockIdx.x * 256 + threadIdx.x;
    if (i < total) {
        __half h = __float2half_rn(src[i]);
        dst[i] = __builtin_bit_cast(ushort_t, h);
    }
}

// coarse bucket histograms: dst over NT items, src over NE edges. LDS-privatized.
__global__ __launch_bounds__(256) void k_binhist(const int* __restrict__ ei,
                                                 int* __restrict__ gbh_d,
                                                 int* __restrict__ gbh_s) {
    __shared__ int hd[NBUCK], hs[NBUCK];
    int tid = threadIdx.x;
    for (int b = tid; b < NBUCK; b += 256) { hd[b] = 0; hs[b] = 0; }
    __syncthreads();
    for (int idx = blockIdx.x * 256 + tid; idx < NT; idx += gridDim.x * 256) {
        int d = (idx < NE) ? ei[NE + idx] : idx - NE;
        atomicAdd(&hd[d >> 8], 1);
        if (idx < NE) atomicAdd(&hs[ei[idx] >> 8], 1);
    }
    __syncthreads();
    for (int b = tid; b < NBUCK; b += 256) {
        if (hd[b]) atomicAdd(&gbh_d[b], hd[b]);
        if (hs[b]) atomicAdd(&gbh_s[b], hs[b]);
    }
}

// scan both 391-entry histograms -> bases [NBUCK+1] and cursors
__global__ void k_scan391(const int* __restrict__ gbh_d, const int* __restrict__ gbh_s,
                          int* __restrict__ bb_d, int* __restrict__ cur_d,
                          int* __restrict__ bb_s, int* __restrict__ cur_s) {
    __shared__ int s[512];
    const int* g = blockIdx.x ? gbh_s : gbh_d;
    int* bb = blockIdx.x ? bb_s : bb_d;
    int* cur = blockIdx.x ? cur_s : cur_d;
    int t = threadIdx.x;
    int v = (t < NBUCK) ? g[t] : 0;
    s[t] = v;
    __syncthreads();
    for (int off = 1; off < 512; off <<= 1) {
        int val = (t >= off) ? s[t - off] : 0;
        __syncthreads();
        s[t] += val;
        __syncthreads();
    }
    if (t < NBUCK) { int e = s[t] - v; bb[t] = e; cur[t] = e; }
    if (t == 511) bb[NBUCK] = s[511];
}

// merged scatter: one pass over ei emits dst-records (NT) AND src-records (NE)
#define CHUNK 4096
__global__ __launch_bounds__(256) void k_scat2(const int* __restrict__ ei,
                                               const int* __restrict__ ea,
                                               int* __restrict__ cur_d,
                                               int* __restrict__ cur_s,
                                               uint_t* __restrict__ rec_d,
                                               int* __restrict__ rec_s) {
    __shared__ int lhd[NBUCK], lbd[NBUCK], lhs[NBUCK], lbs[NBUCK];
    int tid = threadIdx.x;
    for (int b = tid; b < NBUCK; b += 256) { lhd[b] = 0; lhs[b] = 0; }
    __syncthreads();
    int base = blockIdx.x * CHUNK;
    uint_t rd[16];
    int rs[16], bkd[16], bks[16];
#pragma unroll
    for (int k = 0; k < 16; ++k) {
        int idx = base + tid + k * 256;
        bkd[k] = -1; bks[k] = -1;
        if (idx < NT) {
            int s, d, eid;
            if (idx < NE) {
                s = ei[idx]; d = ei[NE + idx]; eid = ea[idx];
                bks[k] = s >> 8; rs[k] = s;
                atomicAdd(&lhs[bks[k]], 1);
            } else {
                s = d = idx - NE; eid = 0;
            }
            bkd[k] = d >> 8;
            rd[k] = (uint_t)s | ((uint_t)eid << 17) | ((uint_t)(d & 255) << 24);
            atomicAdd(&lhd[bkd[k]], 1);
        }
    }
    __syncthreads();
    for (int b = tid; b < NBUCK; b += 256) {
        if (lhd[b]) lbd[b] = atomicAdd(&cur_d[b], lhd[b]);
        if (lhs[b]) lbs[b] = atomicAdd(&cur_s[b], lhs[b]);
    }
    __syncthreads();
    for (int b = tid; b < NBUCK; b += 256) { lhd[b] = 0; lhs[b] = 0; }
    __syncthreads();
#pragma unroll
    for (int k = 0; k < 16; ++k) {
        if (bkd[k] >= 0) {
            int rk = atomicAdd(&lhd[bkd[k]], 1);
            rec_d[lbd[bkd[k]] + rk] = rd[k];
        }
        if (bks[k] >= 0) {
            int rk = atomicAdd(&lhs[bks[k]], 1);
            rec_s[lbs[bks[k]] + rk] = rs[k];
        }
    }
}

// per-bucket exact src histogram -> dinv (deg = count + 1 self-loop)
__global__ __launch_bounds__(256) void k_srcfin(const int* __restrict__ rec,
                                                const int* __restrict__ bb,
                                                float* __restrict__ dinv) {
    __shared__ int h[256];
    int tid = threadIdx.x;
    h[tid] = 0;
    __syncthreads();
    int lo = bb[blockIdx.x], hi = bb[blockIdx.x + 1];
    for (int i = lo + tid; i < hi; i += 256) atomicAdd(&h[rec[i] & 255], 1);
    __syncthreads();
    int v = blockIdx.x * 256 + tid;
    if (v < NN) dinv[v] = rsqrtf((float)(h[tid] + 1));
}

// per-bucket: exact dst hist -> row_ptr; ranked re-scatter -> final CSR.
// norm stored PRE-PACKED as half2 (both lanes = norm).
__global__ __launch_bounds__(256) void k_dstfin(const uint_t* __restrict__ rec,
                                                const int* __restrict__ bb,
                                                const float* __restrict__ dinv,
                                                int* __restrict__ row_ptr,
                                                int* __restrict__ s_pack,
                                                uint_t* __restrict__ s_normh) {
    __shared__ int h[256], sc[256], rpE[256];
    int tid = threadIdx.x;
    h[tid] = 0;
    __syncthreads();
    int lo = bb[blockIdx.x], hi = bb[blockIdx.x + 1];
    for (int i = lo + tid; i < hi; i += 256) atomicAdd(&h[(rec[i] >> 24) & 255], 1);
    __syncthreads();
    sc[tid] = h[tid];
    __syncthreads();
    for (int off = 1; off < 256; off <<= 1) {
        int val = (tid >= off) ? sc[tid - off] : 0;
        __syncthreads();
        sc[tid] += val;
        __syncthreads();
    }
    rpE[tid] = sc[tid] - h[tid];       // exclusive
    int v = blockIdx.x * 256 + tid;
    if (v < NN) row_ptr[v] = lo + rpE[tid];
    h[tid] = 0;
    __syncthreads();
    for (int i = lo + tid; i < hi; i += 256) {
        uint_t u = rec[i];
        int dl = (u >> 24) & 255;
        int rk = atomicAdd(&h[dl], 1);
        int slot = lo + rpE[dl] + rk;
        int s = u & 0x1FFFF;
        int e = (u >> 17) & 0x3F;
        float nm = dinv[s] * dinv[(blockIdx.x << 8) + dl];
        s_pack[slot] = s | (e << 20);
        s_normh[slot] = h22u(__half2half2(__float2half_rn(nm)));
    }
}

// h0 -> fp16 Xh
__global__ void k_h0b(const int* __restrict__ x, const float* __restrict__ emb,
                      ushort_t* __restrict__ Xh, int n) {
    int v = blockIdx.x * 16 + (threadIdx.x >> 4);
    if (v >= n) return;
    int c8 = (threadIdx.x & 15) * 8;
    const float* src = &emb[x[v] * DD + c8];
    uint_t pk[4];
#pragma unroll
    for (int j = 0; j < 4; ++j) pk[j] = pkh(src[2 * j], src[2 * j + 1]);
    *(uint4*)&Xh[(size_t)v * DD + c8] = make_uint4(pk[0], pk[1], pk[2], pk[3]);
}

// ---------------- per-layer kernels ----------------

// apply BN(scale,shift)+optional ReLU to 8 packed fp16, repack to h8 frag
static __device__ __forceinline__ h8 bn8h(uint4 v, float4 sc0, float4 sc1,
                                          float4 sh0, float4 sh1, int relu) {
    const uint_t* pv = (const uint_t*)&v;
    float f[8];
    float2 t;
    t = __half22float2(u2h2(pv[0])); f[0] = t.x; f[1] = t.y;
    t = __half22float2(u2h2(pv[1])); f[2] = t.x; f[3] = t.y;
    t = __half22float2(u2h2(pv[2])); f[4] = t.x; f[5] = t.y;
    t = __half22float2(u2h2(pv[3])); f[6] = t.x; f[7] = t.y;
    f[0] = fmaf(f[0], sc0.x, sh0.x); f[1] = fmaf(f[1], sc0.y, sh0.y);
    f[2] = fmaf(f[2], sc0.z, sh0.z); f[3] = fmaf(f[3], sc0.w, sh0.w);
    f[4] = fmaf(f[4], sc1.x, sh1.x); f[5] = fmaf(f[5], sc1.y, sh1.y);
    f[6] = fmaf(f[6], sc1.z, sh1.z); f[7] = fmaf(f[7], sc1.w, sh1.w);
    if (relu) {
#pragma unroll
        for (int j = 0; j < 8; ++j) f[j] = fmaxf(f[j], 0.f);
    }
    uint4 r;
    r.x = pkh(f[0], f[1]); r.y = pkh(f[2], f[3]);
    r.z = pkh(f[4], f[5]); r.w = pkh(f[6], f[7]);
    return __builtin_bit_cast(h8, r);
}

// LDS-free MFMA fp16 GEMM with swapped operands (packed row-major stores).
__global__ __launch_bounds__(256, 3) void k_gemm(const ushort_t* __restrict__ Xh,
                                                 const ushort_t* __restrict__ Wh,
                                                 const float* __restrict__ bias,
                                                 const float* __restrict__ scale,
                                                 const float* __restrict__ shift,
                                                 ushort_t* __restrict__ C,
                                                 int n, int relu) {
    const int tid = threadIdx.x;
    const int r0 = blockIdx.x * 128;
    const int w = tid >> 6;           // wave 0..3 -> rows w*32..+32
    const int lane = tid & 63;
    const int lr = lane & 15;         // X-row / W-row within 16
    const int lg = lane >> 4;         // k-subgroup 0..3

    f32x4 acc[2][8];
#pragma unroll
    for (int rf = 0; rf < 2; ++rf)
#pragma unroll
        for (int cf = 0; cf < 8; ++cf)
#pragma unroll
            for (int r = 0; r < 4; ++r) acc[rf][cf][r] = 0.f;

#pragma unroll
    for (int ks = 0; ks < 4; ++ks) {
        const int kb = (ks * 4 + lg) * 8;          // this lane's k-base (8 fp16)
        float4 sc0 = ld4(&scale[kb]), sc1 = ld4(&scale[kb + 4]);
        float4 sh0 = ld4(&shift[kb]), sh1 = ld4(&shift[kb + 4]);

        int row0 = r0 + w * 32 + lr;
        int row1 = row0 + 16;
        uint4 va = make_uint4(0, 0, 0, 0), vb = make_uint4(0, 0, 0, 0);
        if (row0 < n) va = *(const uint4*)&Xh[(size_t)row0 * DD + kb];
        if (row1 < n) vb = *(const uint4*)&Xh[(size_t)row1 * DD + kb];
        h8 a0 = bn8h(va, sc0, sc1, sh0, sh1, relu);
        h8 a1 = bn8h(vb, sc0, sc1, sh0, sh1, relu);

#pragma unroll
        for (int cf = 0; cf < 8; ++cf) {
            int col = cf * 16 + lr;
            h8 b = *(const h8*)&Wh[(size_t)col * DD + kb];
            // swapped: W as "A" (D-rows = W-cols), X as "B" (D-cols = X-rows)
            acc[0][cf] = __builtin_amdgcn_mfma_f32_16x16x32_f16(b, a0, acc[0][cf], 0, 0, 0);
            acc[1][cf] = __builtin_amdgcn_mfma_f32_16x16x32_f16(b, a1, acc[1][cf], 0, 0, 0);
        }
    }

    // epilogue: lane owns output row (r0+w*32+rf*16+lr), cols cf*16+lg*4+{0..3}
#pragma unroll
    for (int rf = 0; rf < 2; ++rf) {
        int grow = r0 + w * 32 + rf * 16 + lr;
        if (grow < n) {
#pragma unroll
            for (int cf = 0; cf < 8; ++cf) {
                int c0 = cf * 16 + lg * 4;
                float4 bi = ld4(&bias[c0]);
                uint_t lo = pkh(acc[rf][cf][0] + bi.x, acc[rf][cf][1] + bi.y);
                uint_t hi = pkh(acc[rf][cf][2] + bi.z, acc[rf][cf][3] + bi.w);
                *(uint2*)&C[(size_t)grow * DD + c0] = make_uint2(lo, hi);
            }
        }
    }
}

// agg + fused BN partials. 16 lanes/node, 4x batched gathers, packed fp16 math.
__global__ __launch_bounds__(256) void k_agg(const ushort_t* __restrict__ hl,
                                             const ushort_t* __restrict__ etab,
                                             const int* __restrict__ row_ptr,
                                             const int* __restrict__ s_pack,
                                             const uint_t* __restrict__ s_normh,
                                             ushort_t* __restrict__ aggb,
                                             float* __restrict__ psumA,
                                             float* __restrict__ psumB, int n) {
    __shared__ float lsA[4][DD], lsB[4][DD];
    int tid = threadIdx.x;

    int v = blockIdx.x * 16 + (tid >> 4);      // always < n (exact grid)
    int lane8 = (tid & 15) * 8;
    int p0 = row_ptr[v], p1 = row_ptr[v + 1];
    __half2 acc4[4];
#pragma unroll
    for (int j = 0; j < 4; ++j) acc4[j] = u2h2(0u);

    int p = p0;
    for (; p + 4 <= p1; p += 4) {
        int c0 = s_pack[p], c1 = s_pack[p + 1], c2 = s_pack[p + 2], c3 = s_pack[p + 3];
        uint_t n0 = s_normh[p], n1 = s_normh[p + 1];
        uint_t n2 = s_normh[p + 2], n3 = s_normh[p + 3];
        uint4 h0 = *(const uint4*)&hl[(size_t)(c0 & 0xFFFFF) * DD + lane8];
        uint4 h1 = *(const uint4*)&hl[(size_t)(c1 & 0xFFFFF) * DD + lane8];
        uint4 h2 = *(const uint4*)&hl[(size_t)(c2 & 0xFFFFF) * DD + lane8];
        uint4 h3 = *(const uint4*)&hl[(size_t)(c3 & 0xFFFFF) * DD + lane8];
        uint4 e0 = *(const uint4*)&etab[(c0 >> 20) * DD + lane8];
        uint4 e1 = *(const uint4*)&etab[(c1 >> 20) * DD + lane8];
        uint4 e2 = *(const uint4*)&etab[(c2 >> 20) * DD + lane8];
        uint4 e3 = *(const uint4*)&etab[(c3 >> 20) * DD + lane8];
        accumh(acc4, h0, e0, n0);
        accumh(acc4, h1, e1, n1);
        accumh(acc4, h2, e2, n2);
        accumh(acc4, h3, e3, n3);
    }
    for (; p < p1; ++p) {
        int c = s_pack[p];
        uint_t nr = s_normh[p];
        uint4 hv = *(const uint4*)&hl[(size_t)(c & 0xFFFFF) * DD + lane8];
        uint4 ev = *(const uint4*)&etab[(c >> 20) * DD + lane8];
        accumh(acc4, hv, ev, nr);
    }

    // store packed fp16 agg directly
    uint4 st;
    st.x = h22u(acc4[0]); st.y = h22u(acc4[1]);
    st.z = h22u(acc4[2]); st.w = h22u(acc4[3]);
    *(uint4*)&aggb[(size_t)v * DD + lane8] = st;

    // BN partials in f32
    float f[8];
    float2 t;
    t = __half22float2(acc4[0]); f[0] = t.x; f[1] = t.y;
    t = __half22float2(acc4[1]); f[2] = t.x; f[3] = t.y;
    t = __half22float2(acc4[2]); f[4] = t.x; f[5] = t.y;
    t = __half22float2(acc4[3]); f[6] = t.x; f[7] = t.y;

    float s0[8], s1[8];
#pragma unroll
    for (int j = 0; j < 8; ++j) { s0[j] = f[j]; s1[j] = f[j] * f[j]; }
#pragma unroll
    for (int m = 16; m <= 32; m <<= 1) {
#pragma unroll
        for (int j = 0; j < 8; ++j) {
            s0[j] += __shfl_xor(s0[j], m);
            s1[j] += __shfl_xor(s1[j], m);
        }
    }
    int wv = tid >> 6;
    int lane = tid & 63;
    if (lane < 16) {
#pragma unroll
        for (int j = 0; j < 8; ++j) {
            lsA[wv][lane8 + j] = s0[j];
            lsB[wv][lane8 + j] = s1[j];
        }
    }
    __syncthreads();
    if (tid < DD) {
        psumA[(size_t)blockIdx.x * DD + tid] =
            lsA[0][tid] + lsA[1][tid] + lsA[2][tid] + lsA[3][tid];
        psumB[(size_t)blockIdx.x * DD + tid] =
            lsB[0][tid] + lsB[1][tid] + lsB[2][tid] + lsB[3][tid];
    }
}

// stage-1 BN reduce: coalesced row reads, 128 blocks x 49 rows
__global__ __launch_bounds__(256) void k_bnred(const float* __restrict__ psumA,
                                               const float* __restrict__ psumB,
                                               float* __restrict__ partA,
                                               float* __restrict__ partB) {
    __shared__ float sa[2][DD], sb[2][DD];
    int d = threadIdx.x & 127;
    int half = threadIdx.x >> 7;
    float a = 0.f, b = 0.f;
    int iend = min(blockIdx.x * 49 + 49, PSUMNB);
    for (int i = blockIdx.x * 49 + half; i < iend; i += 2) {
        a += psumA[(size_t)i * DD + d];
        b += psumB[(size_t)i * DD + d];
    }
    sa[half][d] = a; sb[half][d] = b;
    __syncthreads();
    if (threadIdx.x < DD) {
        partA[blockIdx.x * DD + d] = sa[0][d] + sa[1][d];
        partB[blockIdx.x * DD + d] = sb[0][d] + sb[1][d];
    }
}

// final BN: reduce RED1 partials, emit scale/shift
__global__ __launch_bounds__(256) void k_bnfin(const float* __restrict__ partA,
                                               const float* __restrict__ partB,
                                               const float* __restrict__ gamma,
                                               const float* __restrict__ beta,
                                               float* __restrict__ scale,
                                               float* __restrict__ shift, int n) {
    __shared__ float sa[2][DD], sb[2][DD];
    int d = threadIdx.x & 127;
    int half = threadIdx.x >> 7;
    float a = 0.f, b = 0.f;
    for (int i = half; i < RED1; i += 2) {
        a += partA[i * DD + d];
        b += partB[i * DD + d];
    }
    sa[half][d] = a; sb[half][d] = b;
    __syncthreads();
    if (threadIdx.x < DD) {
        float s = sa[0][d] + sa[1][d];
        float ss = sb[0][d] + sb[1][d];
        float mean = s / (float)n;
        float var = ss / (float)n - mean * mean;
        float sc = gamma[d] * rsqrtf(var + BN_EPS);
        scale[d] = sc;
        shift[d] = beta[d] - mean * sc;
    }
}

// final: out = fp16 Xh * scale + shift (fp32)
__global__ void k_bnapply(const ushort_t* __restrict__ Xh, float* __restrict__ out,
                          const float* __restrict__ scale,
                          const float* __restrict__ shift, int total8) {
    int i = blockIdx.x * blockDim.x + threadIdx.x;
    int stride = gridDim.x * blockDim.x;
    for (; i < total8; i += stride) {
        int c8 = (i & 15) * 8;
        uint4 v = *(const uint4*)&Xh[(size_t)i * 8];
        float4 sc0 = ld4(&scale[c8]), sc1 = ld4(&scale[c8 + 4]);
        float4 sh0 = ld4(&shift[c8]), sh1 = ld4(&shift[c8 + 4]);
        float2 t0 = __half22float2(u2h2(v.x));
        float2 t1 = __half22float2(u2h2(v.y));
        float2 t2 = __half22float2(u2h2(v.z));
        float2 t3 = __half22float2(u2h2(v.w));
        float4 o0, o1;
        o0.x = fmaf(t0.x, sc0.x, sh0.x);
        o0.y = fmaf(t0.y, sc0.y, sh0.y);
        o0.z = fmaf(t1.x, sc0.z, sh0.z);
        o0.w = fmaf(t1.y, sc0.w, sh0.w);
        o1.x = fmaf(t2.x, sc1.x, sh1.x);
        o1.y = fmaf(t2.y, sc1.y, sh1.y);
        o1.z = fmaf(t3.x, sc1.z, sh1.z);
        o1.w = fmaf(t3.y, sc1.w, sh1.w);
        *(float4*)&out[(size_t)i * 8] = o0;
        *(float4*)&out[(size_t)i * 8 + 4] = o1;
    }
}

// ---------------- launch ----------------

extern "C" void kernel_launch(void* const* d_in, const int* in_sizes, int n_in,
                              void* d_out, int out_size, void* d_ws, size_t ws_size,
                              hipStream_t stream) {
    const int* x        = (const int*)d_in[0];
    const int* ei       = (const int*)d_in[1];
    const int* ea       = (const int*)d_in[2];
    const float* x_emb  = (const float*)d_in[3];
    const float* lin_w  = (const float*)d_in[4];
    const float* lin_b  = (const float*)d_in[5];
    const float* etab   = (const float*)d_in[6];
    const float* gamma  = (const float*)d_in[7];
    const float* beta   = (const float*)d_in[8];
    float* OUT = (float*)d_out;

    char* w = (char*)d_ws;
    size_t off = 0;
    auto alloc = [&](size_t bytes) -> void* {
        off = (off + 255) & ~(size_t)255;
        void* p = w + off;
        off += bytes;
        return p;
    };
    ushort_t* Xh     = (ushort_t*)alloc((size_t)NN * DD * 2);
    ushort_t* hl     = (ushort_t*)alloc((size_t)NN * DD * 2);
    ushort_t* etabh  = (ushort_t*)alloc((size_t)NL * NB * DD * 2);
    ushort_t* Wh     = (ushort_t*)alloc((size_t)NL * DD * DD * 2);
    uint_t* rec_d    = (uint_t*)alloc((size_t)NT * 4);
    int*    rec_s    = (int*)alloc((size_t)NE * 4);
    int*   s_pack    = (int*)alloc((size_t)NT * 4);
    uint_t* s_normh  = (uint_t*)alloc((size_t)NT * 4);
    int*   rowp      = (int*)alloc((size_t)(NN + 1) * 4);
    float* dinv      = (float*)alloc((size_t)NN * 4);
    int*   gbh_d     = (int*)alloc((size_t)NBUCK * 4);
    int*   gbh_s     = (int*)alloc((size_t)NBUCK * 4);
    int*   bb_d      = (int*)alloc((size_t)(NBUCK + 1) * 4);
    int*   bb_s      = (int*)alloc((size_t)(NBUCK + 1) * 4);
    int*   cur_d     = (int*)alloc((size_t)NBUCK * 4);
    int*   cur_s     = (int*)alloc((size_t)NBUCK * 4);
    float* psumA     = (float*)alloc((size_t)DD * PSUMNB * 4);
    float* psumB     = (float*)alloc((size_t)DD * PSUMNB * 4);
    float* partA     = (float*)alloc((size_t)DD * RED1 * 4);
    float* partB     = (float*)alloc((size_t)DD * RED1 * 4);
    float* scale     = (float*)alloc((size_t)DD * 4);
    float* shift     = (float*)alloc((size_t)DD * 4);

    const int etabTot = NL * NB * DD;
    const int wTot = NL * DD * DD;

    k_init<<<(NN + 255) / 256, 256, 0, stream>>>(gbh_d, gbh_s, scale, shift, rowp);
    k_cvt<<<(etabTot + 255) / 256, 256, 0, stream>>>(etab, etabh, etabTot);
    k_cvt<<<(wTot + 255) / 256, 256, 0, stream>>>(lin_w, Wh, wTot);
    k_binhist<<<256, 256, 0, stream>>>(ei, gbh_d, gbh_s);
    k_scan391<<<2, 512, 0, stream>>>(gbh_d, gbh_s, bb_d, cur_d, bb_s, cur_s);
    k_scat2<<<(NT + CHUNK - 1) / CHUNK, 256, 0, stream>>>(ei, ea, cur_d, cur_s,
                                                          rec_d, rec_s);
    k_srcfin<<<NBUCK, 256, 0, stream>>>(rec_s, bb_s, dinv);
    k_dstfin<<<NBUCK, 256, 0, stream>>>(rec_d, bb_d, dinv, rowp, s_pack, s_normh);
    k_h0b<<<(NN + 15) / 16, 256, 0, stream>>>(x, x_emb, Xh, NN);

    for (int l = 0; l < NL; ++l) {
        k_gemm<<<(NN + 127) / 128, 256, 0, stream>>>(Xh, Wh + (size_t)l * DD * DD,
                                                     lin_b + (size_t)l * DD,
                                                     scale, shift, hl, NN, l > 0 ? 1 : 0);
        k_agg<<<PSUMNB, 256, 0, stream>>>(hl, etabh + (size_t)l * NB * DD,
                                          rowp, s_pack, s_normh, Xh, psumA, psumB, NN);
        k_bnred<<<RED1, 256, 0, stream>>>(psumA, psumB, partA, partB);
        k_bnfin<<<1, 256, 0, stream>>>(partA, partB, gamma + (size_t)l * DD,
                                       beta + (size_t)l * DD, scale, shift, NN);
    }
    k_bnapply<<<(NN * DD / 8 + 255) / 256, 256, 0, stream>>>(Xh, OUT, scale, shift,
                                                             NN * DD / 8);
}